// Round 19
// baseline (225.782 us; speedup 1.0000x reference)
//
#include <hip/hip_runtime.h>
#include <hip/hip_bf16.h>

// SIREN + Fourier-features fused forward, MI355X (gfx950). Round 19.
// = round 18 (191.7us best) with the k-loop switched to 32x32x16 MFMA
// (2495 TF vs 2076 TF measured: largest pipe term -17%, loop MFMA count
// halved 128->64, LDS/W bytes identical). Per wave: 2x2 tiles of 32x32,
// acc = 2x2 x f32x16 = 64 regs (unchanged). Layouts (K-doubling extension
// of the HW-verified 16x16x32 pattern; C/D per m74/m101):
//   A: lane l -> W[j=l&31][k=(l>>5)*8+t]
//   B: lane l -> h[r=l&31][k=(l>>5)*8+t]
//   D: r = l&31, j = (g&3) + 8*(g>>2) + 4*(l>>5), g in [0,16)
// h-tile byte format [r][j] unchanged -> Fourier stage and the final
// 16x16x32 layer are byte-identical to r18. Keeps r16 algebra (pre-scaled
// W/bias, C-in=bias, no fract) and r18's pre-bar2 W prefetch.

typedef __attribute__((ext_vector_type(8))) short bf16x8;
typedef __attribute__((ext_vector_type(4))) float f32x4;
typedef __attribute__((ext_vector_type(16))) float f32x16;

#define NTOTAL 262144
#define BM 64
#define HD 256
#define INV2PI 0.15915494309189535f

__device__ __forceinline__ unsigned short f2bf(float f) {
    unsigned int u = __float_as_uint(f);
    u += 0x7FFFu + ((u >> 16) & 1u);   // RNE (convert kernel only)
    return (unsigned short)(u >> 16);
}

// pack two floats -> 2xbf16 in one u32 (low = a, high = b), compiler-backed
__device__ __forceinline__ unsigned int pk2(float a, float b) {
    __hip_bfloat162 h = __float22bfloat162_rn(make_float2(a, b));
    union { __hip_bfloat162 h; unsigned int u; } c;
    c.h = h;
    return c.u;
}

// swizzled byte offset into the [64][256] bf16 LDS tile (row stride 512B).
// XOR spans bits 4-7: bijective per row; conflicts ~2-way (free).
__device__ __forceinline__ int a_off(int r, int byte) {
    return r * 512 + (byte ^ ((r & 15) << 4));
}

// ---------------- kernel 1: weight conversion + fragment packing ----------------
// wb (bf16 elems): 5 layers x 65536 W' fragment-packed for 32x32x16
// (frag = jg*16 + ks, jg = j>>5 in [0,8), ks = k>>4 in [0,16); within:
// lane = (hi<<5)|(j&31) with hi = (k>>3)&1, elem t = k&7), W' pre-scaled by
// omega/2pi (layer0 also x sqrt2). Then Wf row-major 16x256 zero-pad
// (elems 327680..331775), then 5x256 f32 scaled biases b' (byte 663552).
__global__ void convert_w(const float* __restrict__ W0, const float* __restrict__ Wh,
                          const float* __restrict__ Wf, const float* __restrict__ b0,
                          const float* __restrict__ bh, unsigned short* __restrict__ wb) {
    const int i = blockIdx.x * 256 + threadIdx.x;      // grid 1280 -> 327680
    if (i < 327680) {
        const int l = i >> 16, rem = i & 65535;
        const int j = rem >> 8, k = rem & 255;
        const float sc = (l == 0) ? (1.41421356237309515f * 30.0f * INV2PI) : INV2PI;
        const float v = ((l == 0) ? W0[rem] : Wh[i - 65536]) * sc;
        const int jg = j >> 5, jr = j & 31;
        const int ks = k >> 4, hi = (k >> 3) & 1, t = k & 7;
        const int dst = (l << 16) + (((jg << 4) + ks) << 9) + (((hi << 5) + jr) << 3) + t;
        wb[dst] = f2bf(v);
    }
    if (i < 4096)
        wb[327680 + i] = (i < 512) ? f2bf(Wf[i]) : (unsigned short)0;
    if (i < 1280) {   // scaled bias table (f32)
        const int l = i >> 8, j = i & 255;
        const float sc = (l == 0) ? (30.0f * INV2PI) : INV2PI;
        float* bsc = (float*)(wb + 331776);
        bsc[i] = ((l == 0) ? b0[j] : bh[i - 256]) * sc;
    }
}

// ---------------- kernel 2: fused model ----------------
__global__ __launch_bounds__(256, 3) void siren_fused(
    const float* __restrict__ x, const float* __restrict__ scales,
    const float* __restrict__ Bm, const float* __restrict__ bfin,
    const unsigned short* __restrict__ wb, float* __restrict__ out) {

    __shared__ __align__(16) unsigned short A[BM * HD];

    const int tid  = threadIdx.x;
    const int lane = tid & 63;
    const int wid  = tid >> 6;          // wave 0..3 owns neurons wid*64..+63
    const int row0 = blockIdx.x * BM;
    const int ln31 = lane & 31;
    const int hi   = lane >> 5;         // 0..1
    const int arow = lane & 15;         // final-layer 16x16 indices
    const int q    = lane >> 4;
    const float* bsc = (const float*)(wb + 331776);

    // ---- preload layer-0 ks=0 A-fragments (overlap Fourier stage) ----
    bf16x8 wabuf[2][2];
    #pragma unroll
    for (int jt2 = 0; jt2 < 2; ++jt2)
        wabuf[0][jt2] = *(const bf16x8*)(wb + (((wid * 2 + jt2) << 4) << 9) + lane * 8);

    // ---- Fourier feature stage (fp32; sqrt2 folded into W0'; no fract) ----
    {
        const int r  = tid >> 2;            // 0..63
        const int c0 = (tid & 3) * 32;      // 32 freqs per thread
        const float* xr = x + (row0 + r) * 3;
        const float x0 = xr[0] * scales[0] * INV2PI;
        const float x1 = xr[1] * scales[1] * INV2PI;
        const float x2 = xr[2] * scales[2] * INV2PI;
        #pragma unroll
        for (int cc = 0; cc < 32; cc += 8) {
            const int c = c0 + cc;
            float sv[8], cv[8];
            #pragma unroll
            for (int t = 0; t < 8; ++t) {
                const float rev = x0 * Bm[c + t] + x1 * Bm[128 + c + t] + x2 * Bm[256 + c + t];
                sv[t] = __builtin_amdgcn_sinf(rev);   // |rev| < ~50 rev, in-domain
                cv[t] = __builtin_amdgcn_cosf(rev);
            }
            uint4 us, uc;
            us.x = pk2(sv[0], sv[1]); us.y = pk2(sv[2], sv[3]);
            us.z = pk2(sv[4], sv[5]); us.w = pk2(sv[6], sv[7]);
            uc.x = pk2(cv[0], cv[1]); uc.y = pk2(cv[2], cv[3]);
            uc.z = pk2(cv[4], cv[5]); uc.w = pk2(cv[6], cv[7]);
            *(uint4*)((char*)A + a_off(r, 2 * c))         = us;
            *(uint4*)((char*)A + a_off(r, 2 * (c + 128))) = uc;
        }
    }

    // ---- 5 dense layers (32x32x16 MFMA) ----
    #pragma unroll 1
    for (int layer = 0; layer < 5; ++layer) {
        const unsigned short* Wl = wb + (layer << 16);
        const float* bl = bsc + layer * HD;

        __syncthreads();   // bar1: h tile ready

        // acc C-in = scaled bias: reg g of tile (jt2,rt2) holds
        // j = wid*64 + jt2*32 + 8*(g>>2) + 4*hi + (g&3)
        f32x16 acc[2][2];
        #pragma unroll
        for (int jt2 = 0; jt2 < 2; ++jt2) {
            #pragma unroll
            for (int g2 = 0; g2 < 4; ++g2) {
                const float4 bv = *(const float4*)(bl + wid * 64 + jt2 * 32 + g2 * 8 + hi * 4);
                #pragma unroll
                for (int rt2 = 0; rt2 < 2; ++rt2) {
                    acc[jt2][rt2][g2 * 4 + 0] = bv.x;
                    acc[jt2][rt2][g2 * 4 + 1] = bv.y;
                    acc[jt2][rt2][g2 * 4 + 2] = bv.z;
                    acc[jt2][rt2][g2 * 4 + 3] = bv.w;
                }
            }
        }

        #pragma unroll
        for (int ks = 0; ks < 16; ++ks) {
            const int cur = ks & 1, nxt = cur ^ 1;
            // B fragments: lane -> h[r = rt2*32 + ln31][k = ks*16 + hi*8 + t]
            bf16x8 hb[2];
            #pragma unroll
            for (int rt2 = 0; rt2 < 2; ++rt2)
                hb[rt2] = *(const bf16x8*)((const char*)A +
                    a_off(rt2 * 32 + ln31, ks * 32 + hi * 16));
            if (ks < 15) {
                #pragma unroll
                for (int jt2 = 0; jt2 < 2; ++jt2)
                    wabuf[nxt][jt2] = *(const bf16x8*)(Wl +
                        ((((wid * 2 + jt2) << 4) + ks + 1) << 9) + lane * 8);
            }
            #pragma unroll
            for (int jt2 = 0; jt2 < 2; ++jt2)
                #pragma unroll
                for (int rt2 = 0; rt2 < 2; ++rt2)
                    acc[jt2][rt2] = __builtin_amdgcn_mfma_f32_32x32x16_bf16(
                        wabuf[cur][jt2], hb[rt2], acc[jt2][rt2], 0, 0, 0);
        }

        // prefetch next layer's ks=0 A-fragments BEFORE bar2 (r18 win):
        // global->reg only; wabuf[0] dead (ks=15 consumed wabuf[1]).
        if (layer < 4) {
            const unsigned short* Wn = wb + ((layer + 1) << 16);
            #pragma unroll
            for (int jt2 = 0; jt2 < 2; ++jt2)
                wabuf[0][jt2] = *(const bf16x8*)(Wn + (((wid * 2 + jt2) << 4) << 9) + lane * 8);
        }

        __syncthreads();   // bar2: all reads of h done; safe to overwrite

        // epilogue: h = sin(2*pi*acc); D layout r = ln31, j per reg group
        #pragma unroll
        for (int jt2 = 0; jt2 < 2; ++jt2) {
            #pragma unroll
            for (int rt2 = 0; rt2 < 2; ++rt2) {
                const int r = rt2 * 32 + ln31;
                #pragma unroll
                for (int g2 = 0; g2 < 4; ++g2) {
                    const int j0 = wid * 64 + jt2 * 32 + g2 * 8 + hi * 4;
                    const float s0 = __builtin_amdgcn_sinf(acc[jt2][rt2][g2 * 4 + 0]);
                    const float s1 = __builtin_amdgcn_sinf(acc[jt2][rt2][g2 * 4 + 1]);
                    const float s2 = __builtin_amdgcn_sinf(acc[jt2][rt2][g2 * 4 + 2]);
                    const float s3 = __builtin_amdgcn_sinf(acc[jt2][rt2][g2 * 4 + 3]);
                    uint2 val;
                    val.x = pk2(s0, s1);
                    val.y = pk2(s2, s3);
                    *(uint2*)((char*)A + a_off(r, j0 * 2)) = val;
                }
            }
        }
    }

    __syncthreads();   // final h ready

    // ---- final linear 256 -> 2 (16x16x32, unchanged; tile format identical) ----
    {
        const unsigned short* Wfp = wb + 327680;   // row-major [16][256], zero-padded
        f32x4 acc = (f32x4)(0.0f);
        #pragma unroll
        for (int kt = 0; kt < 8; ++kt) {
            const bf16x8 ff = *(const bf16x8*)(Wfp + arow * HD + kt * 32 + q * 8);
            const bf16x8 hf = *(const bf16x8*)((const char*)A +
                a_off(wid * 16 + arow, kt * 64 + q * 16));
            acc = __builtin_amdgcn_mfma_f32_16x16x32_bf16(ff, hf, acc, 0, 0, 0);
        }
        if (q == 0) {   // lanes 0-15 hold D rows j=0..3; j=0,1 are the two outputs
            const int rg = row0 + wid * 16 + arow;
            float2 o;
            o.x = acc[0] + bfin[0];
            o.y = acc[1] + bfin[1];
            *(float2*)(out + rg * 2) = o;
        }
    }
}

extern "C" void kernel_launch(void* const* d_in, const int* in_sizes, int n_in,
                              void* d_out, int out_size, void* d_ws, size_t ws_size,
                              hipStream_t stream) {
    (void)in_sizes; (void)n_in; (void)out_size; (void)ws_size;
    const float* x      = (const float*)d_in[0];
    const float* scales = (const float*)d_in[1];
    const float* Bm     = (const float*)d_in[2];
    const float* W0     = (const float*)d_in[3];
    const float* b0     = (const float*)d_in[4];
    const float* Wh     = (const float*)d_in[5];
    const float* bh     = (const float*)d_in[6];
    const float* Wf     = (const float*)d_in[7];
    const float* bf     = (const float*)d_in[8];
    unsigned short* wb  = (unsigned short*)d_ws;   // needs 668672 B

    hipLaunchKernelGGL(convert_w, dim3(1280), dim3(256), 0, stream,
                       W0, Wh, Wf, b0, bh, wb);
    hipLaunchKernelGGL(siren_fused, dim3(NTOTAL / BM), dim3(256), 0, stream,
                       x, scales, Bm, bf, wb, (float*)d_out);
}

// Round 20
// 192.537 us; speedup vs baseline: 1.1727x; 1.1727x over previous
//
#include <hip/hip_runtime.h>
#include <hip/hip_bf16.h>

// SIREN + Fourier-features fused forward, MI355X (gfx950). Round 20.
// = round 18 (191.7us best; r19's 32x32 MFMA reverted — 4-MFMA fetch rounds
// broke latency cover, the r14 lesson again) + ONE change: s_setprio(1)
// around the k-loop MFMA region (T5). Null on lockstep GEMM but +4-7% when
// co-resident waves are at different phases (m190/m191) — our 3 independent
// blocks/CU decorrelate naturally (proven r13), matching the attn case.

typedef __attribute__((ext_vector_type(8))) short bf16x8;
typedef __attribute__((ext_vector_type(4))) float f32x4;

#define NTOTAL 262144
#define BM 64
#define HD 256
#define INV2PI 0.15915494309189535f

__device__ __forceinline__ unsigned short f2bf(float f) {
    unsigned int u = __float_as_uint(f);
    u += 0x7FFFu + ((u >> 16) & 1u);   // RNE (convert kernel only)
    return (unsigned short)(u >> 16);
}

// pack two floats -> 2xbf16 in one u32 (low = a, high = b), compiler-backed
__device__ __forceinline__ unsigned int pk2(float a, float b) {
    __hip_bfloat162 h = __float22bfloat162_rn(make_float2(a, b));
    union { __hip_bfloat162 h; unsigned int u; } c;
    c.h = h;
    return c.u;
}

// swizzled byte offset into the [64][256] bf16 LDS tile (row stride 512B).
// XOR spans bits 4-7: bijective per row; write conflicts 2-way (free).
__device__ __forceinline__ int a_off(int r, int byte) {
    return r * 512 + (byte ^ ((r & 15) << 4));
}

// ---------------- kernel 1: weight conversion + fragment packing ----------------
// wb (bf16 elems): 5 layers x 65536 fragment-packed W' (pre-scaled by omega/2pi;
// layer0 also x sqrt2), then Wf row-major 16x256 zero-pad (elems 327680..331775),
// then 5x256 f32 scaled biases b' at byte offset 663552.
__global__ void convert_w(const float* __restrict__ W0, const float* __restrict__ Wh,
                          const float* __restrict__ Wf, const float* __restrict__ b0,
                          const float* __restrict__ bh, unsigned short* __restrict__ wb) {
    const int i = blockIdx.x * 256 + threadIdx.x;      // grid 1280 -> 327680
    if (i < 327680) {
        const int l = i >> 16, rem = i & 65535;
        const int j = rem >> 8, k = rem & 255;
        const float sc = (l == 0) ? (1.41421356237309515f * 30.0f * INV2PI) : INV2PI;
        const float v = ((l == 0) ? W0[rem] : Wh[i - 65536]) * sc;
        const int jt = j >> 4, kt = k >> 5, q = (k >> 3) & 3, r = j & 15, t = k & 7;
        const int dst = (l << 16) + (((jt << 3) + kt) << 9) + (((q << 4) + r) << 3) + t;
        wb[dst] = f2bf(v);
    }
    if (i < 4096)
        wb[327680 + i] = (i < 512) ? f2bf(Wf[i]) : (unsigned short)0;
    if (i < 1280) {   // scaled bias table (f32)
        const int l = i >> 8, j = i & 255;
        const float sc = (l == 0) ? (30.0f * INV2PI) : INV2PI;
        float* bsc = (float*)(wb + 331776);
        bsc[i] = ((l == 0) ? b0[j] : bh[i - 256]) * sc;
    }
}

// ---------------- kernel 2: fused model ----------------
__global__ __launch_bounds__(256, 3) void siren_fused(
    const float* __restrict__ x, const float* __restrict__ scales,
    const float* __restrict__ Bm, const float* __restrict__ bfin,
    const unsigned short* __restrict__ wb, float* __restrict__ out) {

    __shared__ __align__(16) unsigned short A[BM * HD];

    const int tid  = threadIdx.x;
    const int lane = tid & 63;
    const int wid  = tid >> 6;          // wave 0..3 owns neurons wid*64..+63
    const int row0 = blockIdx.x * BM;
    const int arow = lane & 15;
    const int q    = lane >> 4;         // 0..3
    const int kq   = q * 8;
    const float* bsc = (const float*)(wb + 331776);

    // ---- preload layer-0 kt=0 W fragments (overlap Fourier stage) ----
    bf16x8 wfbuf[2][4];
    #pragma unroll
    for (int jt = 0; jt < 4; ++jt)
        wfbuf[0][jt] = *(const bf16x8*)(wb + (((wid * 4 + jt) << 3) << 9) + lane * 8);

    // ---- Fourier feature stage (fp32; sqrt2 folded into W0'; no fract) ----
    {
        const int r  = tid >> 2;            // 0..63
        const int c0 = (tid & 3) * 32;      // 32 freqs per thread
        const float* xr = x + (row0 + r) * 3;
        const float x0 = xr[0] * scales[0] * INV2PI;
        const float x1 = xr[1] * scales[1] * INV2PI;
        const float x2 = xr[2] * scales[2] * INV2PI;
        #pragma unroll
        for (int cc = 0; cc < 32; cc += 8) {
            const int c = c0 + cc;
            float sv[8], cv[8];
            #pragma unroll
            for (int t = 0; t < 8; ++t) {
                const float rev = x0 * Bm[c + t] + x1 * Bm[128 + c + t] + x2 * Bm[256 + c + t];
                sv[t] = __builtin_amdgcn_sinf(rev);   // |rev| < ~50 rev, in-domain
                cv[t] = __builtin_amdgcn_cosf(rev);
            }
            uint4 us, uc;
            us.x = pk2(sv[0], sv[1]); us.y = pk2(sv[2], sv[3]);
            us.z = pk2(sv[4], sv[5]); us.w = pk2(sv[6], sv[7]);
            uc.x = pk2(cv[0], cv[1]); uc.y = pk2(cv[2], cv[3]);
            uc.z = pk2(cv[4], cv[5]); uc.w = pk2(cv[6], cv[7]);
            *(uint4*)((char*)A + a_off(r, 2 * c))         = us;
            *(uint4*)((char*)A + a_off(r, 2 * (c + 128))) = uc;
        }
    }

    // ---- 5 dense layers ----
    #pragma unroll 1
    for (int layer = 0; layer < 5; ++layer) {
        const unsigned short* Wl = wb + (layer << 16);
        const float* bl = bsc + layer * HD;

        __syncthreads();   // bar1: h tile ready

        // acc initialized with the scaled bias (C-in = b')
        f32x4 acc[4][4];
        #pragma unroll
        for (int jt = 0; jt < 4; ++jt) {
            const float4 bv = *(const float4*)(bl + wid * 64 + jt * 16 + q * 4);
            #pragma unroll
            for (int rt = 0; rt < 4; ++rt) {
                acc[jt][rt][0] = bv.x; acc[jt][rt][1] = bv.y;
                acc[jt][rt][2] = bv.z; acc[jt][rt][3] = bv.w;
            }
        }

        __builtin_amdgcn_s_setprio(1);   // T5: favor MFMA-phase waves
        #pragma unroll
        for (int kt = 0; kt < 8; ++kt) {
            const int cur = kt & 1, nxt = cur ^ 1;
            bf16x8 hf[4];
            #pragma unroll
            for (int rt = 0; rt < 4; ++rt)
                hf[rt] = *(const bf16x8*)((const char*)A +
                    a_off(rt * 16 + arow, kt * 64 + q * 16));
            if (kt < 7) {
                #pragma unroll
                for (int jt = 0; jt < 4; ++jt)
                    wfbuf[nxt][jt] = *(const bf16x8*)(Wl +
                        ((((wid * 4 + jt) << 3) + kt + 1) << 9) + lane * 8);
            }
            #pragma unroll
            for (int jt = 0; jt < 4; ++jt)
                #pragma unroll
                for (int rt = 0; rt < 4; ++rt)
                    acc[jt][rt] = __builtin_amdgcn_mfma_f32_16x16x32_bf16(
                        wfbuf[cur][jt], hf[rt], acc[jt][rt], 0, 0, 0);
        }
        __builtin_amdgcn_s_setprio(0);

        // prefetch next layer's kt=0 W fragments BEFORE bar2 (r18 win)
        if (layer < 4) {
            const unsigned short* Wn = wb + ((layer + 1) << 16);
            #pragma unroll
            for (int jt = 0; jt < 4; ++jt)
                wfbuf[0][jt] = *(const bf16x8*)(Wn + (((wid * 4 + jt) << 3) << 9) + lane * 8);
        }

        __syncthreads();   // bar2: all reads of h done; safe to overwrite

        // epilogue: h = sin(2*pi*acc) — bare v_sin + pack (bias/scale pre-folded)
        #pragma unroll
        for (int jt = 0; jt < 4; ++jt) {
            const int jj = wid * 64 + jt * 16 + q * 4;   // 4 consecutive neurons
            #pragma unroll
            for (int rt = 0; rt < 4; ++rt) {
                const int r = rt * 16 + arow;
                const float s0 = __builtin_amdgcn_sinf(acc[jt][rt][0]);
                const float s1 = __builtin_amdgcn_sinf(acc[jt][rt][1]);
                const float s2 = __builtin_amdgcn_sinf(acc[jt][rt][2]);
                const float s3 = __builtin_amdgcn_sinf(acc[jt][rt][3]);
                uint2 val;
                val.x = pk2(s0, s1);
                val.y = pk2(s2, s3);
                *(uint2*)((char*)A + a_off(r, jj * 2)) = val;
            }
        }
    }

    __syncthreads();   // final h ready

    // ---- final linear 256 -> 2, distributed: wave w handles rows w*16..+15 ----
    {
        const unsigned short* Wfp = wb + 327680;   // row-major [16][256], zero-padded
        f32x4 acc = (f32x4)(0.0f);
        #pragma unroll
        for (int kt = 0; kt < 8; ++kt) {
            const bf16x8 ff = *(const bf16x8*)(Wfp + arow * HD + kt * 32 + kq);
            const bf16x8 hf = *(const bf16x8*)((const char*)A +
                a_off(wid * 16 + arow, kt * 64 + q * 16));
            acc = __builtin_amdgcn_mfma_f32_16x16x32_bf16(ff, hf, acc, 0, 0, 0);
        }
        if (q == 0) {   // lanes 0-15 hold D rows j=0..3; j=0,1 are the two outputs
            const int rg = row0 + wid * 16 + arow;
            float2 o;
            o.x = acc[0] + bfin[0];
            o.y = acc[1] + bfin[1];
            *(float2*)(out + rg * 2) = o;
        }
    }
}

extern "C" void kernel_launch(void* const* d_in, const int* in_sizes, int n_in,
                              void* d_out, int out_size, void* d_ws, size_t ws_size,
                              hipStream_t stream) {
    (void)in_sizes; (void)n_in; (void)out_size; (void)ws_size;
    const float* x      = (const float*)d_in[0];
    const float* scales = (const float*)d_in[1];
    const float* Bm     = (const float*)d_in[2];
    const float* W0     = (const float*)d_in[3];
    const float* b0     = (const float*)d_in[4];
    const float* Wh     = (const float*)d_in[5];
    const float* bh     = (const float*)d_in[6];
    const float* Wf     = (const float*)d_in[7];
    const float* bf     = (const float*)d_in[8];
    unsigned short* wb  = (unsigned short*)d_ws;   // needs 668672 B

    hipLaunchKernelGGL(convert_w, dim3(1280), dim3(256), 0, stream,
                       W0, Wh, Wf, b0, bh, wb);
    hipLaunchKernelGGL(siren_fused, dim3(NTOTAL / BM), dim3(256), 0, stream,
                       x, scales, Bm, bf, wb, (float*)d_out);
}